// Round 3
// baseline (304.682 us; speedup 1.0000x reference)
//
#include <hip/hip_runtime.h>

// Problem constants (from reference)
#define VOCAB 32000
#define D     64
#define B     32
#define S     512
#define NCHUNK 16    // number of time chunks
#define CLEN   32    // chunk length (S / NCHUNK)

typedef float vf4 __attribute__((ext_vector_type(4)));

#define DECAY  0.9f
// 0.9^32, computed in double then rounded: ((0.81^2)^2)^2 ^2 chain
#define DECAYC 0.034336838202925312f

// ---------------------------------------------------------------------------
// Pass 1: gather content[b,s,:] = emb[x[b,s],:]   (float4 vectorized)
// 1024 blocks x 256 threads. ~8 MB of traffic, ~3 us. Staging keeps the two
// hot passes reading LINEAR, L2-resident data instead of token gathers.
// ---------------------------------------------------------------------------
__global__ void qmn_gather(const int* __restrict__ x,
                           const vf4* __restrict__ emb4,
                           vf4* __restrict__ content4) {
    int tid = blockIdx.x * blockDim.x + threadIdx.x;   // [0, B*S*16)
    int bs  = tid >> 4;
    int d4  = tid & 15;
    int tok = x[bs];
    content4[tid] = emb4[tok * (D / 4) + d4];
}

// ---------------------------------------------------------------------------
// Pass 2: per-chunk partials  P[b,c] = sum_{tt<CLEN} 0.9^(CLEN-1-tt) p_{c*CLEN+tt}
// All 16 chunks in parallel (scan is linear). 2048 blocks x 256 thr, 32 steps.
// Single 16B store at the end -> no store stream to couple with.
// ---------------------------------------------------------------------------
__global__ __launch_bounds__(256, 4) void qmn_partial(
    const float* __restrict__ content,   // [B, S, D]
    vf4*        __restrict__ P4)         // [B, NCHUNK, D, D/4]
{
    int blk   = blockIdx.x;
    int c     = blk & 15;
    int b     = (blk >> 4) & 31;
    int iBase = (blk >> 9) * 16;

    int jq = threadIdx.x & 15;
    int i  = iBase + (threadIdx.x >> 4);

    const float* cb  = content + (size_t)b * S * D;
    const vf4*   cb4 = (const vf4*)cb;
    const int    t0  = c * CLEN;

    vf4 acc; acc.x = 0.f; acc.y = 0.f; acc.z = 0.f; acc.w = 0.f;

    #pragma unroll 8
    for (int tt = 0; tt < CLEN; ++tt) {
        int t = t0 + tt;
        float ci = cb[t * D + i];
        vf4   cj = cb4[t * (D / 4) + jq];
        acc.x = acc.x * DECAY + ci * cj.x;
        acc.y = acc.y * DECAY + ci * cj.y;
        acc.z = acc.z * DECAY + ci * cj.z;
        acc.w = acc.w * DECAY + ci * cj.w;
    }

    P4[(((b * NCHUNK + c) * D) + i) * (D / 4) + jq] = acc;
}

// ---------------------------------------------------------------------------
// Pass 3: prefix over the 16 chunks.
//   R[b,0] = I;  R[b,c] = 0.9^CLEN * R[b,c-1] + P[b,c-1]
// One thread per (b, i, jq): 32768 threads = 128 blocks. ~3 us.
// ---------------------------------------------------------------------------
__global__ __launch_bounds__(256) void qmn_prefix(
    const vf4* __restrict__ P4,   // [B, NCHUNK, D, D/4]
    vf4*       __restrict__ R4)   // [B, NCHUNK, D, D/4]
{
    int tid = blockIdx.x * 256 + threadIdx.x;   // [0, B*D*16)
    int jq  = tid & 15;
    int i   = (tid >> 4) & 63;
    int b   = tid >> 10;

    // identity slice
    vf4 r;
    int j0 = jq * 4;
    r.x = (i == j0 + 0) ? 1.0f : 0.0f;
    r.y = (i == j0 + 1) ? 1.0f : 0.0f;
    r.z = (i == j0 + 2) ? 1.0f : 0.0f;
    r.w = (i == j0 + 3) ? 1.0f : 0.0f;

    const vf4* Pb  = P4 + (size_t)b * NCHUNK * D * (D / 4);
    vf4*       Rb  = R4 + (size_t)b * NCHUNK * D * (D / 4);
    const int  off = i * (D / 4) + jq;

    Rb[off] = r;   // c = 0

    #pragma unroll
    for (int c = 1; c < NCHUNK; ++c) {
        vf4 p = Pb[(c - 1) * D * (D / 4) + off];
        r.x = r.x * DECAYC + p.x;
        r.y = r.y * DECAYC + p.y;
        r.z = r.z * DECAYC + p.z;
        r.w = r.w * DECAYC + p.w;
        Rb[c * D * (D / 4) + off] = r;
    }
}

// ---------------------------------------------------------------------------
// Pass 4: store kernel. KEY CHANGE vs round 1: the chunk's content slice is
// staged into LDS FIRST, so the hot loop has NO global loads — only LDS reads
// (lgkmcnt) + nontemporal stores (vmcnt). Loads and stores share the in-order
// vmcnt queue on CDNA: a loop that waits on per-step content loads forcibly
// drains its own store stream every iteration (the round-1 ~2.3 TB/s). With
// LDS-only reads the 256 MiB store stream free-runs like the fill kernel.
// 2048 blocks -> 8 blocks/CU x 4 waves = 32 waves/CU (launch_bounds 256,8).
// LDS reads are broadcast / b128 over all banks -> conflict-free.
// ---------------------------------------------------------------------------
__global__ __launch_bounds__(256, 8) void qmn_store(
    const float* __restrict__ content,   // [B, S, D]
    const vf4*  __restrict__ R4,         // [B, NCHUNK, D, D/4]
    vf4*        __restrict__ out4)       // [B, S, D, D] as float4 over j
{
    __shared__ vf4 lds4[CLEN * D / 4];   // 8 KiB: the chunk's content slice
    float* ldsf = (float*)lds4;

    int blk   = blockIdx.x;
    int c     = blk & 15;                // consecutive blocks: different chunk
    int b     = (blk >> 4) & 31;
    int iBase = (blk >> 9) * 16;         // iBase replicas 512 apart -> same XCD

    int jq = threadIdx.x & 15;
    int i  = iBase + (threadIdx.x >> 4);

    const int tStart = c * CLEN;

    // ---- stage chunk content into LDS (linear, coalesced) ----
    const vf4* cb4 = (const vf4*)(content + (size_t)b * S * D);
    #pragma unroll
    for (int k = 0; k < CLEN * D / 4 / 256; ++k) {
        int idx = k * 256 + threadIdx.x;
        lds4[idx] = cb4[tStart * (D / 4) + idx];
    }

    vf4 rho = R4[(((b * NCHUNK + c) * D) + i) * (D / 4) + jq];

    __syncthreads();

    // ---- 32 steps: LDS reads + FMA + nontemporal float4 store ----
    vf4* outp = out4 + (((size_t)(b * S + tStart)) * D + i) * (D / 4) + jq;

    #pragma unroll 4
    for (int tt = 0; tt < CLEN; ++tt) {
        float ci = ldsf[tt * D + i];         // broadcast within jq-group
        vf4   cj = lds4[tt * (D / 4) + jq];  // 256B row, b128 reads
        rho.x = rho.x * DECAY + ci * cj.x;
        rho.y = rho.y * DECAY + ci * cj.y;
        rho.z = rho.z * DECAY + ci * cj.z;
        rho.w = rho.w * DECAY + ci * cj.w;
        __builtin_nontemporal_store(rho, outp);
        outp += D * (D / 4);                 // next t: +16 KiB
    }
}

// ---------------------------------------------------------------------------
// Launch
// ---------------------------------------------------------------------------
extern "C" void kernel_launch(void* const* d_in, const int* in_sizes, int n_in,
                              void* d_out, int out_size, void* d_ws, size_t ws_size,
                              hipStream_t stream) {
    const int*   x   = (const int*)d_in[0];     // [B, S] token ids
    const float* emb = (const float*)d_in[1];   // [VOCAB, D]
    vf4* out = (vf4*)d_out;                     // [B, S, D, D]

    // workspace layout: content (4 MiB) | P (8 MiB) | R (8 MiB)
    float* content = (float*)d_ws;
    vf4*   P4 = (vf4*)((char*)d_ws + (size_t)B * S * D * sizeof(float));
    vf4*   R4 = (vf4*)((char*)d_ws + (size_t)B * S * D * sizeof(float)
                                   + (size_t)B * NCHUNK * D * D * sizeof(float));

    qmn_gather<<<B * S * (D / 4) / 256, 256, 0, stream>>>(
        x, (const vf4*)emb, (vf4*)content);

    qmn_partial<<<B * NCHUNK * 4, 256, 0, stream>>>(content, P4);

    qmn_prefix<<<(B * D * 16) / 256, 256, 0, stream>>>(P4, R4);

    qmn_store<<<B * NCHUNK * 4, 256, 0, stream>>>(content, R4, out);
}

// Round 7
// 292.830 us; speedup vs baseline: 1.0405x; 1.0405x over previous
//
#include <hip/hip_runtime.h>

// Problem constants (from reference)
#define VOCAB 32000
#define D     64
#define B     32
#define S     512
#define NCHUNK 16    // number of time chunks
#define CLEN   32    // chunk length (S / NCHUNK)

typedef float vf4 __attribute__((ext_vector_type(4)));

#define DECAY  0.9f
// 0.9^32, computed in double then rounded
#define DECAYC 0.034336838202925312f

// ---------------------------------------------------------------------------
// Two-kernel pipeline (was four). Both kernels stage their chunk's embedding
// rows DIRECTLY from emb via the token ids into LDS (one 8 KiB staging pass
// per block), eliminating the qmn_gather kernel and the content buffer
// round-trip. The prefix kernel is folded into the store kernel's prologue
// (<=15 L2-resident vf4 loads per thread). Rationale: rounds 0-3 showed the
// pipeline structure is worth ~nothing -- the timed region is dominated by
// ~213 us of harness poison fills + a ~44 us write-roofline store; the only
// remaining recoverable cost is small-kernel time + inter-launch gaps.
// ---------------------------------------------------------------------------

// ---------------------------------------------------------------------------
// Kernel A: per-chunk partials  P[b,c] = sum_{tt<CLEN} 0.9^(CLEN-1-tt) p_t
// 2048 blocks (b, c, iBase) x 256 threads. Stages chunk emb rows into LDS,
// 32 accumulate steps, one 16B store. ~8 us.
// ---------------------------------------------------------------------------
__global__ __launch_bounds__(256, 8) void qmn_partial(
    const int* __restrict__ x,      // [B, S] token ids
    const vf4* __restrict__ emb4,   // [VOCAB, D/4]
    vf4*       __restrict__ P4)     // [B, NCHUNK, D, D/4]
{
    __shared__ vf4 lds4[CLEN * D / 4];   // 8 KiB: the chunk's content slice
    float* ldsf = (float*)lds4;

    int blk   = blockIdx.x;
    int c     = blk & 15;
    int b     = (blk >> 4) & 31;
    int iBase = (blk >> 9) * 16;

    int jq = threadIdx.x & 15;
    int i  = iBase + (threadIdx.x >> 4);
    const int tStart = c * CLEN;

    // ---- stage chunk emb rows into LDS (token gather, L3-resident emb) ----
    #pragma unroll
    for (int k = 0; k < CLEN * (D / 4) / 256; ++k) {
        int idx = k * 256 + threadIdx.x;          // [0, 512)
        int tok = x[b * S + tStart + (idx >> 4)];
        lds4[idx] = emb4[tok * (D / 4) + (idx & 15)];
    }
    __syncthreads();

    vf4 acc; acc.x = 0.f; acc.y = 0.f; acc.z = 0.f; acc.w = 0.f;

    #pragma unroll
    for (int tt = 0; tt < CLEN; ++tt) {
        float ci = ldsf[tt * D + i];          // broadcast within 16-lane group
        vf4   cj = lds4[tt * (D / 4) + jq];   // 256B row, b128 reads
        acc.x = acc.x * DECAY + ci * cj.x;
        acc.y = acc.y * DECAY + ci * cj.y;
        acc.z = acc.z * DECAY + ci * cj.z;
        acc.w = acc.w * DECAY + ci * cj.w;
    }

    P4[(((b * NCHUNK + c) * D) + i) * (D / 4) + jq] = acc;
}

// ---------------------------------------------------------------------------
// Kernel B: store kernel with INLINE prefix.
//   R[b,c] = DECAYC^c * I + sum_{k<c} DECAYC^(c-1-k) * P[b,k]
// computed per-thread in the prologue (<=15 vf4 loads, L2-resident, done
// while the LDS staging is in flight), then 32 steps of LDS-read + FMA +
// nontemporal coalesced float4 stores. All 2048 blocks store from t=0.
// ---------------------------------------------------------------------------
__global__ __launch_bounds__(256, 8) void qmn_store(
    const int* __restrict__ x,      // [B, S] token ids
    const vf4* __restrict__ emb4,   // [VOCAB, D/4]
    const vf4* __restrict__ P4,     // [B, NCHUNK, D, D/4]
    vf4*       __restrict__ out4)   // [B, S, D, D] as float4 over j
{
    __shared__ vf4 lds4[CLEN * D / 4];   // 8 KiB
    float* ldsf = (float*)lds4;

    int blk   = blockIdx.x;
    int c     = blk & 15;                // consecutive blocks: different chunk
    int b     = (blk >> 4) & 31;
    int iBase = (blk >> 9) * 16;

    int jq = threadIdx.x & 15;
    int i  = iBase + (threadIdx.x >> 4);
    const int tStart = c * CLEN;

    // ---- stage chunk emb rows into LDS ----
    #pragma unroll
    for (int k = 0; k < CLEN * (D / 4) / 256; ++k) {
        int idx = k * 256 + threadIdx.x;
        int tok = x[b * S + tStart + (idx >> 4)];
        lds4[idx] = emb4[tok * (D / 4) + (idx & 15)];
    }

    // ---- inline prefix: rho = R[b,c] for this (i,jq) ----
    vf4 rho;
    int j0 = jq * 4;
    rho.x = (i == j0 + 0) ? 1.0f : 0.0f;
    rho.y = (i == j0 + 1) ? 1.0f : 0.0f;
    rho.z = (i == j0 + 2) ? 1.0f : 0.0f;
    rho.w = (i == j0 + 3) ? 1.0f : 0.0f;

    const vf4* Pb = P4 + ((size_t)b * NCHUNK * D) * (D / 4) + i * (D / 4) + jq;
    for (int k = 0; k < c; ++k) {         // wave-uniform trip count
        vf4 p = Pb[k * D * (D / 4)];
        rho.x = rho.x * DECAYC + p.x;
        rho.y = rho.y * DECAYC + p.y;
        rho.z = rho.z * DECAYC + p.z;
        rho.w = rho.w * DECAYC + p.w;
    }

    __syncthreads();

    // ---- 32 steps: LDS reads + FMA + nontemporal float4 store ----
    vf4* outp = out4 + (((size_t)(b * S + tStart)) * D + i) * (D / 4) + jq;

    #pragma unroll 4
    for (int tt = 0; tt < CLEN; ++tt) {
        float ci = ldsf[tt * D + i];          // broadcast within 16-lane group
        vf4   cj = lds4[tt * (D / 4) + jq];   // 256B row, b128 reads
        rho.x = rho.x * DECAY + ci * cj.x;
        rho.y = rho.y * DECAY + ci * cj.y;
        rho.z = rho.z * DECAY + ci * cj.z;
        rho.w = rho.w * DECAY + ci * cj.w;
        __builtin_nontemporal_store(rho, outp);
        outp += D * (D / 4);                  // next t: +16 KiB
    }
}

// ---------------------------------------------------------------------------
// Launch: two kernels, stream-ordered (partial -> store).
// ---------------------------------------------------------------------------
extern "C" void kernel_launch(void* const* d_in, const int* in_sizes, int n_in,
                              void* d_out, int out_size, void* d_ws, size_t ws_size,
                              hipStream_t stream) {
    const int*   x   = (const int*)d_in[0];     // [B, S] token ids
    const float* emb = (const float*)d_in[1];   // [VOCAB, D]
    vf4* out = (vf4*)d_out;                     // [B, S, D, D]

    vf4* P4 = (vf4*)d_ws;                       // [B, NCHUNK, D, D/4] = 8 MiB

    qmn_partial<<<B * NCHUNK * 4, 256, 0, stream>>>(
        x, (const vf4*)emb, P4);

    qmn_store<<<B * NCHUNK * 4, 256, 0, stream>>>(
        x, (const vf4*)emb, P4, out);
}